// Round 1
// baseline (2539.530 us; speedup 1.0000x reference)
//
#include <hip/hip_runtime.h>
#include <cstdint>
#include <cstddef>

// ---------------- problem constants ----------------
#define NLAYER 4
#define CDIM   512
#define TLEN   1024
#define BSZ    2
#define MROWS  (BSZ * TLEN)   // 2048
#define VOCAB  50257
#define NHEAD  8
#define HDIM   64
#define LORA_S 4.0f

typedef unsigned short ushort_t;
typedef __attribute__((ext_vector_type(8))) short  short8;
typedef __attribute__((ext_vector_type(4))) float  f32x4;
typedef __attribute__((ext_vector_type(4))) unsigned short us4;

// fp32 -> bf16, round-to-nearest-even (finite inputs only)
__device__ inline ushort_t f2bf(float f) {
  union { float f; unsigned u; } c; c.f = f;
  unsigned u = c.u;
  u += 0x7fffu + ((u >> 16) & 1u);
  return (ushort_t)(u >> 16);
}

// async global->LDS, 16B per lane; lds dest = wave-uniform base + lane*16
__device__ inline void stage16(const ushort_t* g, ushort_t* lds) {
  __builtin_amdgcn_global_load_lds(
      (__attribute__((address_space(1))) unsigned int*)(g),
      (__attribute__((address_space(3))) unsigned int*)(lds),
      16, 0, 0);
}

// ---------------- bf16 MFMA GEMM:  C[M,N] = A[M,K] @ B[N,K]^T  (fp32 out) ----
// 128x128 block tile, BK=32, 4 waves each computing a 64x64 subtile (4x4 MFMA).
// M must be a multiple of 128; N guarded (head matmul N=50257); K multiple of 32.
__global__ __launch_bounds__(256) void gemm_bt(const ushort_t* __restrict__ A,
                                               const ushort_t* __restrict__ B,
                                               float* __restrict__ C,
                                               int M, int N, int K) {
  __shared__ ushort_t As[128 * 32];   // 8 KB, row-major [row][k]
  __shared__ ushort_t Bs[128 * 32];   // 8 KB, row-major [n][k]
  const int tid  = threadIdx.x;
  const int wave = tid >> 6, lane = tid & 63;
  const int m0 = blockIdx.y << 7;
  const int n0 = blockIdx.x << 7;
  const int wr = (wave >> 1) << 6;    // wave sub-tile row base (0/64)
  const int wc = (wave & 1) << 6;     // wave sub-tile col base (0/64)
  const int lr = lane & 15;           // fragment row
  const int kq = (lane >> 4) << 3;    // fragment k offset (quad*8)

  f32x4 acc[4][4];
#pragma unroll
  for (int i = 0; i < 4; ++i)
#pragma unroll
    for (int j = 0; j < 4; ++j) {
      acc[i][j][0] = 0.f; acc[i][j][1] = 0.f;
      acc[i][j][2] = 0.f; acc[i][j][3] = 0.f;
    }

  for (int k0 = 0; k0 < K; k0 += 32) {
    __syncthreads();   // protect LDS from previous iteration's readers
    // A tile: 128x32 bf16 = 512 chunks of 16B; thread t stages chunks t, t+256
#pragma unroll
    for (int i = 0; i < 2; ++i) {
      int c = i * 256 + tid;
      int row = c >> 2, col = (c & 3) << 3;
      stage16(A + (size_t)(m0 + row) * K + k0 + col,
              As + ((i * 256 + (wave << 6)) << 3));
    }
#pragma unroll
    for (int i = 0; i < 2; ++i) {
      int c = i * 256 + tid;
      int row = c >> 2, col = (c & 3) << 3;
      int n = n0 + row; if (n > N - 1) n = N - 1;   // clamp (head tail tile)
      stage16(B + (size_t)n * K + k0 + col,
              Bs + ((i * 256 + (wave << 6)) << 3));
    }
    __syncthreads();   // drains vmcnt -> LDS tiles ready

    short8 af[4], bf[4];
#pragma unroll
    for (int i = 0; i < 4; ++i)
      af[i] = *(const short8*)(As + (wr + i * 16 + lr) * 32 + kq);
#pragma unroll
    for (int j = 0; j < 4; ++j)
      bf[j] = *(const short8*)(Bs + (wc + j * 16 + lr) * 32 + kq);
#pragma unroll
    for (int i = 0; i < 4; ++i)
#pragma unroll
      for (int j = 0; j < 4; ++j)
        acc[i][j] = __builtin_amdgcn_mfma_f32_16x16x32_bf16(af[i], bf[j], acc[i][j], 0, 0, 0);
  }

  // epilogue: D mapping col=lane&15, row=(lane>>4)*4+reg
  const int rq = (lane >> 4) << 2;
  const int cl = lane & 15;
#pragma unroll
  for (int i = 0; i < 4; ++i) {
    int mb = m0 + wr + i * 16 + rq;
#pragma unroll
    for (int j = 0; j < 4; ++j) {
      int col = n0 + wc + j * 16 + cl;
      if (col < N) {
        float* cp = C + (size_t)mb * N + col;
#pragma unroll
        for (int r = 0; r < 4; ++r) cp[(size_t)r * N] = acc[i][j][r];
      }
    }
  }
}

// ---------------- weight prep ----------------
// plain fp32 -> bf16 (vectorized x4)
__global__ void conv_bf16(const float* __restrict__ in, ushort_t* __restrict__ out, long n) {
  long i = ((long)blockIdx.x * 256 + threadIdx.x) * 4;
  if (i < n) {
    float4 v = *(const float4*)(in + i);
    us4 o = { f2bf(v.x), f2bf(v.y), f2bf(v.z), f2bf(v.w) };
    *(us4*)(out + i) = o;
  }
}

// W'[l][n][k] = bf16( W + LORA_S * lB[l][n][:8] . lA[l][:8][k] ), K = 512
__global__ void conv_lora(const float* __restrict__ W, const float* __restrict__ lA,
                          const float* __restrict__ lB, ushort_t* __restrict__ out,
                          int N, long total) {
  long i = (long)blockIdx.x * 256 + threadIdx.x;
  if (i >= total) return;
  long nk = (long)N * CDIM;
  int  l  = (int)(i / nk);
  long r  = i - (long)l * nk;
  int  n  = (int)(r >> 9);
  int  k  = (int)(r & 511);
  const float* lAp = lA + (long)l * 8 * CDIM;
  const float* lBp = lB + (long)l * N * 8;
  float acc = W[i];
#pragma unroll
  for (int j = 0; j < 8; ++j) acc += LORA_S * lBp[n * 8 + j] * lAp[j * CDIM + k];
  out[i] = f2bf(acc);
}

// ---------------- embedding ----------------
__global__ void embed_kernel(const int* __restrict__ idx, const float* __restrict__ wte,
                             const float* __restrict__ wpe, float* __restrict__ x) {
  int i = blockIdx.x * 256 + threadIdx.x;   // over MROWS*CDIM = 1M
  int m = i >> 9, c = i & 511;
  int t = m & (TLEN - 1);
  x[i] = wte[(size_t)idx[m] * CDIM + c] + wpe[(size_t)t * CDIM + c];
}

// ---------------- layernorm (fp32 in, bf16 out), one row per block ----------
__global__ __launch_bounds__(256) void ln_kernel(const float* __restrict__ x,
                                                 const float* __restrict__ g,
                                                 const float* __restrict__ b,
                                                 ushort_t* __restrict__ out) {
  const int m = blockIdx.x, tid = threadIdx.x;
  const float2 v = ((const float2*)(x + (size_t)m * CDIM))[tid];
  float s = v.x + v.y, ss = v.x * v.x + v.y * v.y;
#pragma unroll
  for (int off = 32; off; off >>= 1) { s += __shfl_xor(s, off); ss += __shfl_xor(ss, off); }
  __shared__ float rs[4], rss[4];
  const int w = tid >> 6, lane = tid & 63;
  if (lane == 0) { rs[w] = s; rss[w] = ss; }
  __syncthreads();
  s  = rs[0] + rs[1] + rs[2] + rs[3];
  ss = rss[0] + rss[1] + rss[2] + rss[3];
  const float mean = s * (1.f / CDIM);
  const float var  = ss * (1.f / CDIM) - mean * mean;
  const float rstd = rsqrtf(var + 1e-5f);
  const int c = tid * 2;
  out[(size_t)m * CDIM + c]     = f2bf((v.x - mean) * rstd * g[c]     + b[c]);
  out[(size_t)m * CDIM + c + 1] = f2bf((v.y - mean) * rstd * g[c + 1] + b[c + 1]);
}

// ---------------- causal attention, fp32, 8-query tile per block -------------
// grid (TLEN/8, BSZ*NHEAD), block 256
__global__ __launch_bounds__(256) void attn_kernel(const float* __restrict__ qkv,
                                                   float* __restrict__ y) {
  __shared__ float qs[512];        // 8 q rows x 64 (also reused as reduce buf)
  __shared__ float sc[8][TLEN];    // scores/probs, 32 KB
  __shared__ float ssum[8];
  const int tid = threadIdx.x;
  const int t0  = blockIdx.x << 3;
  const int bh  = blockIdx.y;
  const int bb  = bh >> 3, hh = bh & 7;
  const int nk  = t0 + 8;
  const size_t RS = 3 * CDIM;      // 1536

  for (int i = tid; i < 512; i += 256) {
    int r = i >> 6, d = i & 63;
    qs[i] = qkv[(size_t)(bb * TLEN + t0 + r) * RS + hh * 64 + d];
  }
  __syncthreads();

  // scores: each thread owns key k, reads k-row once, dots with 8 q rows
  for (int k = tid; k < nk; k += 256) {
    const float4* kr = (const float4*)(qkv + (size_t)(bb * TLEN + k) * RS + CDIM + hh * 64);
    float4 kv[16];
#pragma unroll
    for (int i = 0; i < 16; ++i) kv[i] = kr[i];
#pragma unroll
    for (int r = 0; r < 8; ++r) {
      const float4* q4 = (const float4*)(qs + r * 64);
      float s = 0.f;
#pragma unroll
      for (int i = 0; i < 16; ++i) {
        float4 q = q4[i];   // LDS broadcast (same addr across lanes)
        s += q.x * kv[i].x + q.y * kv[i].y + q.z * kv[i].z + q.w * kv[i].w;
      }
      sc[r][k] = s * 0.125f;   // 1/sqrt(64)
    }
  }
  __syncthreads();

  // causal softmax per row; each wave handles rows w and w+4
  {
    const int w = tid >> 6, lane = tid & 63;
    for (int r = w; r < 8; r += 4) {
      const int nkr = t0 + r + 1;
      float mx = -1e30f;
      for (int k = lane; k < nkr; k += 64) mx = fmaxf(mx, sc[r][k]);
#pragma unroll
      for (int off = 32; off; off >>= 1) mx = fmaxf(mx, __shfl_xor(mx, off));
      float sum = 0.f;
      for (int k = lane; k < nkr; k += 64) {
        float p = expf(sc[r][k] - mx); sc[r][k] = p; sum += p;
      }
      for (int k = nkr + lane; k < nk; k += 64) sc[r][k] = 0.f;  // mask future keys
#pragma unroll
      for (int off = 32; off; off >>= 1) sum += __shfl_xor(sum, off);
      if (lane == 0) ssum[r] = sum;
    }
  }
  __syncthreads();

  // y = P @ V ; thread = (d, g): dim d, key-stripe g of 4
  const int d = tid & 63, g = tid >> 6;
  float acc[8];
#pragma unroll
  for (int r = 0; r < 8; ++r) acc[r] = 0.f;
  for (int k = g; k < nk; k += 4) {
    float v = qkv[(size_t)(bb * TLEN + k) * RS + 2 * CDIM + hh * 64 + d];
#pragma unroll
    for (int r = 0; r < 8; ++r) acc[r] += sc[r][k] * v;   // sc read = broadcast
  }
#pragma unroll
  for (int r = 0; r < 8; ++r) {
    __syncthreads();
    qs[tid] = acc[r];
    __syncthreads();
    if (g == 0) {
      float yv = (qs[d] + qs[64 + d] + qs[128 + d] + qs[192 + d]) / ssum[r];
      y[(size_t)(bb * TLEN + t0 + r) * CDIM + hh * 64 + d] = yv;
    }
  }
}

// ---------------- elementwise ----------------
// x += delta (+ bias per col, cols=512); n = MROWS*CDIM
__global__ void add_res(float* __restrict__ x, const float* __restrict__ d,
                        const float* __restrict__ bias, int n) {
  int i = blockIdx.x * 256 + threadIdx.x;
  if (i < n) {
    float v = x[i] + d[i];
    if (bias) v += bias[i & 511];
    x[i] = v;
  }
}

// out = bf16(gelu(in + bias[col])), cols = 2048
__global__ void gelu_bias(const float* __restrict__ in, const float* __restrict__ bias,
                          ushort_t* __restrict__ out, int n) {
  int i = blockIdx.x * 256 + threadIdx.x;
  if (i < n) {
    float v = in[i] + bias[i & 2047];
    float t = tanhf(0.7978845608028654f * (v + 0.044715f * v * v * v));
    out[i] = f2bf(0.5f * v * (1.0f + t));
  }
}

// ---------------- launch ----------------
extern "C" void kernel_launch(void* const* d_in, const int* in_sizes, int n_in,
                              void* d_out, int out_size, void* d_ws, size_t ws_size,
                              hipStream_t stream) {
  const int*   idx     = (const int*)  d_in[0];
  const float* wte     = (const float*)d_in[1];
  const float* wpe     = (const float*)d_in[2];
  const float* ln1_g   = (const float*)d_in[3];
  const float* ln1_b   = (const float*)d_in[4];
  const float* attn_w  = (const float*)d_in[5];
  const float* attn_lA = (const float*)d_in[6];
  const float* attn_lB = (const float*)d_in[7];
  const float* proj_w  = (const float*)d_in[8];
  const float* proj_lA = (const float*)d_in[9];
  const float* proj_lB = (const float*)d_in[10];
  const float* ln2_g   = (const float*)d_in[11];
  const float* ln2_b   = (const float*)d_in[12];
  const float* fc_w    = (const float*)d_in[13];
  const float* fc_b    = (const float*)d_in[14];
  const float* mproj_w = (const float*)d_in[15];
  const float* mproj_b = (const float*)d_in[16];
  const float* lnf_g   = (const float*)d_in[17];
  const float* lnf_b   = (const float*)d_in[18];
  const float* head_w  = (const float*)d_in[19];
  float* out = (float*)d_out;

  // workspace carve (256B aligned)
  uintptr_t p = (uintptr_t)d_ws;
  auto take = [&](size_t bytes) -> void* {
    uintptr_t q = p;
    p = (p + bytes + 255) & ~(uintptr_t)255;
    return (void*)q;
  };
  ushort_t* wAttnB  = (ushort_t*)take((size_t)NLAYER * 1536 * 512 * 2);
  ushort_t* wProjB  = (ushort_t*)take((size_t)NLAYER * 512 * 512 * 2);
  ushort_t* wFcB    = (ushort_t*)take((size_t)NLAYER * 2048 * 512 * 2);
  ushort_t* wMprojB = (ushort_t*)take((size_t)NLAYER * 512 * 2048 * 2);
  ushort_t* wHeadB  = (ushort_t*)take((size_t)VOCAB * 512 * 2);
  float*    x       = (float*)   take((size_t)MROWS * 512 * 4);
  ushort_t* hbf     = (ushort_t*)take((size_t)MROWS * 512 * 2);
  float*    qkv     = (float*)   take((size_t)MROWS * 1536 * 4);
  float*    yf      = (float*)   take((size_t)MROWS * 512 * 4);
  ushort_t* ybf     = (ushort_t*)take((size_t)MROWS * 512 * 2);
  float*    tmp     = (float*)   take((size_t)MROWS * 512 * 4);
  float*    fcf     = (float*)   take((size_t)MROWS * 2048 * 4);
  ushort_t* mbf     = (ushort_t*)take((size_t)MROWS * 2048 * 2);

  // ---- weight prep (per launch; LoRA folded into qkv/proj weights) ----
  {
    long nA = (long)NLAYER * 1536 * 512;
    conv_lora<<<(int)((nA + 255) / 256), 256, 0, stream>>>(attn_w, attn_lA, attn_lB, wAttnB, 1536, nA);
    long nP = (long)NLAYER * 512 * 512;
    conv_lora<<<(int)((nP + 255) / 256), 256, 0, stream>>>(proj_w, proj_lA, proj_lB, wProjB, 512, nP);
    long nF = (long)NLAYER * 2048 * 512;
    conv_bf16<<<(int)((nF / 4 + 255) / 256), 256, 0, stream>>>(fc_w, wFcB, nF);
    long nM = (long)NLAYER * 512 * 2048;
    conv_bf16<<<(int)((nM / 4 + 255) / 256), 256, 0, stream>>>(mproj_w, wMprojB, nM);
    long nH = (long)VOCAB * 512;
    conv_bf16<<<(int)((nH / 4 + 255) / 256), 256, 0, stream>>>(head_w, wHeadB, nH);
  }

  // ---- embedding ----
  embed_kernel<<<(MROWS * 512) / 256, 256, 0, stream>>>(idx, wte, wpe, x);

  // ---- transformer layers ----
  for (int l = 0; l < NLAYER; ++l) {
    ln_kernel<<<MROWS, 256, 0, stream>>>(x, ln1_g + l * 512, ln1_b + l * 512, hbf);
    gemm_bt<<<dim3(1536 / 128, MROWS / 128), 256, 0, stream>>>(
        hbf, wAttnB + (size_t)l * 1536 * 512, qkv, MROWS, 1536, 512);
    attn_kernel<<<dim3(TLEN / 8, BSZ * NHEAD), 256, 0, stream>>>(qkv, yf);
    conv_bf16<<<(MROWS * 512 / 4) / 256, 256, 0, stream>>>(yf, ybf, (long)MROWS * 512);
    gemm_bt<<<dim3(512 / 128, MROWS / 128), 256, 0, stream>>>(
        ybf, wProjB + (size_t)l * 512 * 512, tmp, MROWS, 512, 512);
    add_res<<<(MROWS * 512) / 256, 256, 0, stream>>>(x, tmp, nullptr, MROWS * 512);

    ln_kernel<<<MROWS, 256, 0, stream>>>(x, ln2_g + l * 512, ln2_b + l * 512, hbf);
    gemm_bt<<<dim3(2048 / 128, MROWS / 128), 256, 0, stream>>>(
        hbf, wFcB + (size_t)l * 2048 * 512, fcf, MROWS, 2048, 512);
    gelu_bias<<<(MROWS * 2048) / 256, 256, 0, stream>>>(fcf, fc_b + l * 2048, mbf, MROWS * 2048);
    gemm_bt<<<dim3(512 / 128, MROWS / 128), 256, 0, stream>>>(
        mbf, wMprojB + (size_t)l * 512 * 2048, tmp, MROWS, 512, 2048);
    add_res<<<(MROWS * 512) / 256, 256, 0, stream>>>(x, tmp, mproj_b + l * 512, MROWS * 512);
  }

  // ---- final LN + head ----
  ln_kernel<<<MROWS, 256, 0, stream>>>(x, lnf_g, lnf_b, hbf);
  gemm_bt<<<dim3((VOCAB + 127) / 128, MROWS / 128), 256, 0, stream>>>(
      hbf, wHeadB, out, MROWS, VOCAB, 512);
}